// Round 1
// baseline (233.891 us; speedup 1.0000x reference)
//
#include <hip/hip_runtime.h>
#include <hip/hip_bf16.h>

#define EMBED  128
#define HIDDEN 512
#define CHUNK  128   // hidden columns per pass
#define TB     64    // tokens per block

// ---------------------------------------------------------------------------
// Kernel 1: bloom scatter-add  agg[bi[k]][e] += 0.5f * table[bj[k]][e]
// ---------------------------------------------------------------------------
__global__ void bloom_scatter_kernel(const float* __restrict__ table,
                                     const int*   __restrict__ bi,
                                     const int*   __restrict__ bj,
                                     float*       __restrict__ agg,
                                     int nk) {
    int idx = blockIdx.x * blockDim.x + threadIdx.x;
    int total = nk * EMBED;
    if (idx >= total) return;
    int k = idx >> 7;        // which bloom entry
    int e = idx & 127;       // embed element
    int i = bi[k];
    int j = bj[k];
    atomicAdd(&agg[i * EMBED + e], 0.5f * table[j * EMBED + e]);
}

// ---------------------------------------------------------------------------
// Kernel 2: fused gather + MLP:  out = gelu(agg[tok] @ w1 + b1) @ w2 + b2
// 256 threads, 64 tokens per block. Micro-tile 4 rows x 8 cols per thread.
// ---------------------------------------------------------------------------
__device__ __forceinline__ float gelu_tanh(float x) {
    // jax.nn.gelu approximate=True
    float x3 = x * x * x;
    float u  = 0.7978845608028654f * (x + 0.044715f * x3);
    return 0.5f * x * (1.0f + tanhf(u));
}

__global__ __launch_bounds__(256)
void mlp_kernel(const int*   __restrict__ tokens,
                const float* __restrict__ agg,
                const float* __restrict__ w1,
                const float* __restrict__ b1,
                const float* __restrict__ w2,
                const float* __restrict__ b2,
                float*       __restrict__ out) {
    __shared__ float Xs[TB][EMBED];   // 32 KB
    __shared__ float Hs[TB][CHUNK];   // 32 KB

    const int t  = threadIdx.x;
    const int tx = t & 15;            // 16 col-groups of 8
    const int ty = t >> 4;            // 16 row-groups of 4
    const int r0 = ty * 4;            // first of 4 rows this thread owns
    const int c0 = tx * 8;            // first of 8 cols this thread owns
    const int base = blockIdx.x * TB; // first token row of this block

    // ---- stage X = agg[tokens] into LDS (64 rows x 128 f32) ----
    for (int it = 0; it < 8; ++it) {
        int lin = t + it * 256;       // float4 index, 0..2047
        int r   = lin >> 5;           // 0..63
        int e4  = lin & 31;           // 0..31 (float4 within row)
        int tok = tokens[base + r];
        float4 v = *(const float4*)&agg[tok * EMBED + e4 * 4];
        *(float4*)&Xs[r][e4 * 4] = v;
    }
    __syncthreads();

    // ---- output accumulator, init with b2 ----
    float accO[4][8];
    #pragma unroll
    for (int rr = 0; rr < 4; ++rr)
        #pragma unroll
        for (int jj = 0; jj < 8; ++jj)
            accO[rr][jj] = b2[c0 + jj];

    for (int c = 0; c < HIDDEN / CHUNK; ++c) {
        // ---- phase A: Hc = gelu(X @ w1_chunk + b1_chunk) ----
        float accH[4][8];
        #pragma unroll
        for (int rr = 0; rr < 4; ++rr)
            #pragma unroll
            for (int jj = 0; jj < 8; ++jj)
                accH[rr][jj] = b1[c * CHUNK + c0 + jj];

        #pragma unroll 4
        for (int e = 0; e < EMBED; ++e) {
            float x0 = Xs[r0 + 0][e];
            float x1 = Xs[r0 + 1][e];
            float x2 = Xs[r0 + 2][e];
            float x3 = Xs[r0 + 3][e];
            const float* wrow = &w1[e * HIDDEN + c * CHUNK + c0];
            float4 wa = *(const float4*)(wrow);
            float4 wb = *(const float4*)(wrow + 4);
            float w[8] = {wa.x, wa.y, wa.z, wa.w, wb.x, wb.y, wb.z, wb.w};
            #pragma unroll
            for (int jj = 0; jj < 8; ++jj) {
                accH[0][jj] = fmaf(x0, w[jj], accH[0][jj]);
                accH[1][jj] = fmaf(x1, w[jj], accH[1][jj]);
                accH[2][jj] = fmaf(x2, w[jj], accH[2][jj]);
                accH[3][jj] = fmaf(x3, w[jj], accH[3][jj]);
            }
        }

        // gelu + store to Hs
        #pragma unroll
        for (int rr = 0; rr < 4; ++rr) {
            float4 h0, h1;
            h0.x = gelu_tanh(accH[rr][0]);
            h0.y = gelu_tanh(accH[rr][1]);
            h0.z = gelu_tanh(accH[rr][2]);
            h0.w = gelu_tanh(accH[rr][3]);
            h1.x = gelu_tanh(accH[rr][4]);
            h1.y = gelu_tanh(accH[rr][5]);
            h1.z = gelu_tanh(accH[rr][6]);
            h1.w = gelu_tanh(accH[rr][7]);
            *(float4*)&Hs[r0 + rr][c0]     = h0;
            *(float4*)&Hs[r0 + rr][c0 + 4] = h1;
        }
        __syncthreads();

        // ---- phase B: out += Hc @ w2_chunk ----
        #pragma unroll 4
        for (int j = 0; j < CHUNK; ++j) {
            float h0 = Hs[r0 + 0][j];
            float h1 = Hs[r0 + 1][j];
            float h2 = Hs[r0 + 2][j];
            float h3 = Hs[r0 + 3][j];
            const float* wrow = &w2[(c * CHUNK + j) * EMBED + c0];
            float4 wa = *(const float4*)(wrow);
            float4 wb = *(const float4*)(wrow + 4);
            float w[8] = {wa.x, wa.y, wa.z, wa.w, wb.x, wb.y, wb.z, wb.w};
            #pragma unroll
            for (int jj = 0; jj < 8; ++jj) {
                accO[0][jj] = fmaf(h0, w[jj], accO[0][jj]);
                accO[1][jj] = fmaf(h1, w[jj], accO[1][jj]);
                accO[2][jj] = fmaf(h2, w[jj], accO[2][jj]);
                accO[3][jj] = fmaf(h3, w[jj], accO[3][jj]);
            }
        }
        __syncthreads();   // before Hs is overwritten next chunk
    }

    // ---- store out ----
    #pragma unroll
    for (int rr = 0; rr < 4; ++rr) {
        float4 o0 = make_float4(accO[rr][0], accO[rr][1], accO[rr][2], accO[rr][3]);
        float4 o1 = make_float4(accO[rr][4], accO[rr][5], accO[rr][6], accO[rr][7]);
        float* orow = &out[(base + r0 + rr) * EMBED + c0];
        *(float4*)(orow)     = o0;
        *(float4*)(orow + 4) = o1;
    }
}

// ---------------------------------------------------------------------------
extern "C" void kernel_launch(void* const* d_in, const int* in_sizes, int n_in,
                              void* d_out, int out_size, void* d_ws, size_t ws_size,
                              hipStream_t stream) {
    const int*   tokens = (const int*)  d_in[0];
    const float* table  = (const float*)d_in[1];
    const int*   bi     = (const int*)  d_in[2];
    const int*   bj     = (const int*)  d_in[3];
    const float* w1     = (const float*)d_in[4];
    const float* b1     = (const float*)d_in[5];
    const float* w2     = (const float*)d_in[6];
    const float* b2     = (const float*)d_in[7];
    float* out = (float*)d_out;
    float* agg = (float*)d_ws;

    const int vocab = in_sizes[1] / EMBED;   // 50257
    const int nk    = in_sizes[2];           // 4 * vocab
    const int ntok  = in_sizes[0];           // 32768

    // zero the aggregation table
    hipMemsetAsync(agg, 0, (size_t)vocab * EMBED * sizeof(float), stream);

    // scatter-add
    int total  = nk * EMBED;
    int blocks = (total + 255) / 256;
    bloom_scatter_kernel<<<blocks, 256, 0, stream>>>(table, bi, bj, agg, nk);

    // fused gather + MLP
    mlp_kernel<<<ntok / TB, 256, 0, stream>>>(tokens, agg, w1, b1, w2, b2, out);
}

// Round 2
// 136.920 us; speedup vs baseline: 1.7082x; 1.7082x over previous
//
#include <hip/hip_runtime.h>
#include <hip/hip_bf16.h>
#include <stdint.h>

#define EMBED  128
#define HIDDEN 512
#define TB     32    // tokens per block (mlp)

typedef __attribute__((ext_vector_type(8))) short short8v;   // 8 bf16 = 4 VGPR
typedef __attribute__((ext_vector_type(4))) float f32x4;

__device__ __forceinline__ ushort f2bf(float f) {
    // round-to-nearest-even fp32 -> bf16
    uint32_t b = __float_as_uint(f);
    uint32_t r = (b + 0x7FFFu + ((b >> 16) & 1u)) >> 16;
    return (ushort)r;
}

__device__ __forceinline__ float gelu_fast(float x) {
    // 0.5x(1+tanh(u)) == x - x/(exp(2u)+1),  u = 0.79788456(x + 0.044715x^3)
    float x2 = x * x;
    float u  = x * fmaf(0.035677408136f, x2, 0.7978845608f);   // = 0.79788456*(x+0.044715x^3)
    float t  = __expf(2.0f * u);                               // e^(2u)
    return x - x * __frcp_rn(t + 1.0f);
}

// ---------------------------------------------------------------------------
// flags[tok] = 1 for every token present
// ---------------------------------------------------------------------------
__global__ void flag_kernel(const int* __restrict__ tokens, uint8_t* __restrict__ flags, int n) {
    int i = blockIdx.x * blockDim.x + threadIdx.x;
    if (i < n) flags[tokens[i]] = 1;
}

// ---------------------------------------------------------------------------
// wt[n*K + k] = bf16(w[k*N + n])   (transpose + cast)
// ---------------------------------------------------------------------------
__global__ void conv_t_kernel(const float* __restrict__ w, ushort* __restrict__ wt, int K, int N) {
    int idx = blockIdx.x * blockDim.x + threadIdx.x;
    if (idx >= K * N) return;
    int n = idx / K, k = idx - n * K;
    wt[idx] = f2bf(w[k * N + n]);
}

// ---------------------------------------------------------------------------
// bloom scatter-add, skipping rows no token ever gathers
// ---------------------------------------------------------------------------
__global__ void bloom_scatter_kernel(const float* __restrict__ table,
                                     const int*   __restrict__ bi,
                                     const int*   __restrict__ bj,
                                     const uint8_t* __restrict__ flags,
                                     float*       __restrict__ agg,
                                     int nk) {
    int idx = blockIdx.x * blockDim.x + threadIdx.x;
    if (idx >= nk * EMBED) return;
    int k = idx >> 7;          // wave-uniform (128 threads per entry)
    int i = bi[k];
    if (!flags[i]) return;     // wave-uniform early-out
    int e = idx & 127;
    int j = bj[k];
    atomicAdd(&agg[i * EMBED + e], 0.5f * table[j * EMBED + e]);
}

// ---------------------------------------------------------------------------
// fused gather + bf16-MFMA MLP
// 256 threads = 4 waves, 32 tokens/block.
// GEMM1: wave w -> hidden cols [w*128, w*128+128)
// GEMM2: wave w -> out    cols [w*32,  w*32+32)
// ---------------------------------------------------------------------------
__global__ __launch_bounds__(256)
void mlp_mfma_kernel(const int*    __restrict__ tokens,
                     const float*  __restrict__ agg,
                     const ushort* __restrict__ W1t,   // [512][128] bf16
                     const ushort* __restrict__ W2t,   // [128][512] bf16
                     const float*  __restrict__ b1,
                     const float*  __restrict__ b2,
                     float*        __restrict__ out) {
    __shared__ ushort Xs[TB * EMBED];    // 8 KB, XOR-swizzled (granule16 ^= row&7)
    __shared__ ushort Hs[TB * HIDDEN];   // 32 KB, XOR-swizzled

    const int t    = threadIdx.x;
    const int lane = t & 63;
    const int wv   = t >> 6;
    const int base = blockIdx.x * TB;
    const int l15  = lane & 15;
    const int lhi  = lane >> 4;          // 0..3

    // ---- stage X = bf16(agg[tokens]) into swizzled LDS ----
    {
        int r    = t >> 3;               // 0..31
        int cseg = (t & 7) * 16;         // 16 floats per thread
        int tok  = tokens[base + r];
        const float* src = agg + (size_t)tok * EMBED + cseg;
        #pragma unroll
        for (int h = 0; h < 2; ++h) {
            float4 va = *(const float4*)(src + h * 8);
            float4 vb = *(const float4*)(src + h * 8 + 4);
            ushort u[8] = {f2bf(va.x), f2bf(va.y), f2bf(va.z), f2bf(va.w),
                           f2bf(vb.x), f2bf(vb.y), f2bf(vb.z), f2bf(vb.w)};
            int g = ((cseg >> 3) + h) ^ (r & 7);
            *(short8v*)&Xs[r * EMBED + g * 8] = *(short8v*)u;
        }
    }
    __syncthreads();

    // ---- GEMM1: H[32][128 per wave] = X @ W1 ----
    f32x4 acc1[2][8];
    #pragma unroll
    for (int n = 0; n < 8; ++n) {
        float bv = b1[wv * 128 + n * 16 + l15];
        #pragma unroll
        for (int m = 0; m < 2; ++m) acc1[m][n] = (f32x4){bv, bv, bv, bv};
    }

    #pragma unroll
    for (int kk = 0; kk < EMBED / 32; ++kk) {       // 4 k-steps
        short8v a[2];
        #pragma unroll
        for (int m = 0; m < 2; ++m) {
            int r = m * 16 + l15;
            int g = (kk * 4 + lhi) ^ (r & 7);
            a[m] = *(const short8v*)&Xs[r * EMBED + g * 8];
        }
        #pragma unroll
        for (int n = 0; n < 8; ++n) {
            int col = wv * 128 + n * 16 + l15;
            short8v b = *(const short8v*)(W1t + col * EMBED + kk * 32 + lhi * 8);
            acc1[0][n] = __builtin_amdgcn_mfma_f32_16x16x32_bf16(a[0], b, acc1[0][n], 0, 0, 0);
            acc1[1][n] = __builtin_amdgcn_mfma_f32_16x16x32_bf16(a[1], b, acc1[1][n], 0, 0, 0);
        }
    }

    // ---- gelu -> bf16 -> swizzled Hs ----
    #pragma unroll
    for (int m = 0; m < 2; ++m)
        #pragma unroll
        for (int n = 0; n < 8; ++n) {
            int col = wv * 128 + n * 16 + l15;
            #pragma unroll
            for (int q = 0; q < 4; ++q) {
                int row = m * 16 + lhi * 4 + q;
                float hv = gelu_fast(acc1[m][n][q]);
                int g = (col >> 3) ^ (row & 7);
                Hs[row * HIDDEN + g * 8 + (col & 7)] = f2bf(hv);
            }
        }
    __syncthreads();

    // ---- GEMM2: out[32][32 per wave] = H @ W2 ----
    f32x4 acc2[2][2] = {};
    #pragma unroll 4
    for (int kk = 0; kk < HIDDEN / 32; ++kk) {      // 16 k-steps
        short8v a[2];
        #pragma unroll
        for (int m = 0; m < 2; ++m) {
            int r = m * 16 + l15;
            int g = (kk * 4 + lhi) ^ (r & 7);       // XOR hits low 3 bits only
            a[m] = *(const short8v*)&Hs[r * HIDDEN + g * 8];
        }
        #pragma unroll
        for (int n = 0; n < 2; ++n) {
            int col = wv * 32 + n * 16 + l15;
            short8v b = *(const short8v*)(W2t + col * HIDDEN + kk * 32 + lhi * 8);
            acc2[0][n] = __builtin_amdgcn_mfma_f32_16x16x32_bf16(a[0], b, acc2[0][n], 0, 0, 0);
            acc2[1][n] = __builtin_amdgcn_mfma_f32_16x16x32_bf16(a[1], b, acc2[1][n], 0, 0, 0);
        }
    }

    // ---- epilogue: += b2, store ----
    #pragma unroll
    for (int n = 0; n < 2; ++n) {
        int col = wv * 32 + n * 16 + l15;
        float bv = b2[col];
        #pragma unroll
        for (int m = 0; m < 2; ++m)
            #pragma unroll
            for (int q = 0; q < 4; ++q) {
                int row = m * 16 + lhi * 4 + q;
                out[(size_t)(base + row) * EMBED + col] = acc2[m][n][q] + bv;
            }
    }
}

// ---------------------------------------------------------------------------
extern "C" void kernel_launch(void* const* d_in, const int* in_sizes, int n_in,
                              void* d_out, int out_size, void* d_ws, size_t ws_size,
                              hipStream_t stream) {
    const int*   tokens = (const int*)  d_in[0];
    const float* table  = (const float*)d_in[1];
    const int*   bi     = (const int*)  d_in[2];
    const int*   bj     = (const int*)  d_in[3];
    const float* w1     = (const float*)d_in[4];
    const float* b1     = (const float*)d_in[5];
    const float* w2     = (const float*)d_in[6];
    const float* b2     = (const float*)d_in[7];
    float* out = (float*)d_out;

    const int vocab = in_sizes[1] / EMBED;   // 50257
    const int nk    = in_sizes[2];           // 4 * vocab
    const int ntok  = in_sizes[0];           // 32768

    // ws layout
    char* ws = (char*)d_ws;
    float*   agg   = (float*)ws;                               // vocab*128*4 B
    size_t   aggB  = (size_t)vocab * EMBED * sizeof(float);
    ushort*  W1t   = (ushort*)(ws + aggB);                     // 512*128*2 B
    ushort*  W2t   = (ushort*)(ws + aggB + EMBED * HIDDEN * 2);
    uint8_t* flags = (uint8_t*)(ws + aggB + 2 * EMBED * HIDDEN * 2);

    hipMemsetAsync(agg, 0, aggB, stream);
    hipMemsetAsync(flags, 0, vocab, stream);

    flag_kernel<<<(ntok + 255) / 256, 256, 0, stream>>>(tokens, flags, ntok);

    conv_t_kernel<<<(EMBED * HIDDEN + 255) / 256, 256, 0, stream>>>(w1, W1t, EMBED, HIDDEN);
    conv_t_kernel<<<(EMBED * HIDDEN + 255) / 256, 256, 0, stream>>>(w2, W2t, HIDDEN, EMBED);

    int total = nk * EMBED;
    bloom_scatter_kernel<<<(total + 255) / 256, 256, 0, stream>>>(table, bi, bj, flags, agg, nk);

    mlp_mfma_kernel<<<ntok / TB, 256, 0, stream>>>(tokens, agg, W1t, W2t, b1, b2, out);
}

// Round 3
// 90.564 us; speedup vs baseline: 2.5826x; 1.5119x over previous
//
#include <hip/hip_runtime.h>
#include <hip/hip_bf16.h>
#include <stdint.h>

#define EMBED  128
#define HIDDEN 512
#define TB     32    // tokens per block (mlp)
#define CAP    24    // bucket capacity per vocab row (Poisson lambda=4)
#define OVF_MAX 4096

typedef __attribute__((ext_vector_type(8))) short short8v;   // 8 bf16 = 4 VGPR
typedef __attribute__((ext_vector_type(4))) float f32x4;

__device__ __forceinline__ ushort f2bf(float f) {
    // round-to-nearest-even fp32 -> bf16
    uint32_t b = __float_as_uint(f);
    uint32_t r = (b + 0x7FFFu + ((b >> 16) & 1u)) >> 16;
    return (ushort)r;
}
__device__ __forceinline__ float bf2f(ushort u) {
    return __uint_as_float(((uint32_t)u) << 16);
}

__device__ __forceinline__ float gelu_fast(float x) {
    // 0.5x(1+tanh(u)) == x - x/(exp(2u)+1),  u = 0.79788456(x + 0.044715x^3)
    float x2 = x * x;
    float u  = x * fmaf(0.035677408136f, x2, 0.7978845608f);
    float t  = __expf(2.0f * u);
    return x - x * __frcp_rn(t + 1.0f);
}

// ---------------------------------------------------------------------------
// flags[tok]=1; first setter assigns compact row id remap[tok]
// ---------------------------------------------------------------------------
__global__ void flag_remap_kernel(const int* __restrict__ tokens,
                                  int* __restrict__ flags,
                                  int* __restrict__ remap,
                                  int* __restrict__ nuniq, int n) {
    int idx = blockIdx.x * blockDim.x + threadIdx.x;
    if (idx >= n) return;
    int tok = tokens[idx];
    if (atomicExch(&flags[tok], 1) == 0)
        remap[tok] = atomicAdd(nuniq, 1);
}

// ---------------------------------------------------------------------------
// transpose + cast both weight matrices to bf16
// W1t[n*128+k] = w1[k*512+n]   (n<512, k<128)
// W2t[n*512+k] = w2[k*128+n]   (n<128, k<512)
// ---------------------------------------------------------------------------
__global__ void conv_t_kernel(const float* __restrict__ w1, const float* __restrict__ w2,
                              ushort* __restrict__ W1t, ushort* __restrict__ W2t) {
    int idx = blockIdx.x * blockDim.x + threadIdx.x;
    if (idx < EMBED * HIDDEN) {
        int n = idx >> 7, k = idx & 127;
        W1t[idx] = f2bf(w1[k * HIDDEN + n]);
    } else {
        int i2 = idx - EMBED * HIDDEN;
        int n = i2 >> 9, k = i2 & 511;
        W2t[i2] = f2bf(w2[k * EMBED + n]);
    }
}

// ---------------------------------------------------------------------------
// bucket bloom entries by destination row (flagged rows only)
// ---------------------------------------------------------------------------
__global__ void bucket_kernel(const int* __restrict__ bi, const int* __restrict__ bj,
                              const int* __restrict__ flags,
                              int* __restrict__ cnt, int* __restrict__ csr,
                              int2* __restrict__ ovf, int* __restrict__ ovfn, int nk) {
    int k = blockIdx.x * blockDim.x + threadIdx.x;
    if (k >= nk) return;
    int i = bi[k];
    if (!flags[i]) return;
    int slot = atomicAdd(&cnt[i], 1);
    if (slot < CAP) {
        csr[i * CAP + slot] = bj[k];
    } else {
        int p = atomicAdd(ovfn, 1);
        if (p < OVF_MAX) ovf[p] = make_int2(i, bj[k]);
    }
}

// ---------------------------------------------------------------------------
// one wave per flagged vocab row: aggbf[remap[i]] = bf16(0.5 * sum table[j])
// ---------------------------------------------------------------------------
__global__ __launch_bounds__(256)
void agg_build_kernel(const float* __restrict__ table,
                      const int* __restrict__ flags, const int* __restrict__ remap,
                      const int* __restrict__ cnt, const int* __restrict__ csr,
                      ushort* __restrict__ aggbf, int vocab) {
    int wid  = (blockIdx.x * blockDim.x + threadIdx.x) >> 6;   // row
    int lane = threadIdx.x & 63;
    if (wid >= vocab || !flags[wid]) return;
    int m = min(cnt[wid], CAP);
    const int* row = csr + wid * CAP;
    float a0 = 0.f, a1 = 0.f;
    for (int e = 0; e < m; ++e) {
        int j = row[e];
        float2 v = *(const float2*)&table[(size_t)j * EMBED + lane * 2];
        a0 += v.x; a1 += v.y;
    }
    ushort2 o;
    o.x = f2bf(0.5f * a0);
    o.y = f2bf(0.5f * a1);
    *(ushort2*)&aggbf[(size_t)remap[wid] * EMBED + lane * 2] = o;
}

// ---------------------------------------------------------------------------
// overflow fixup (expected count: 0). 1 block, 128 threads (col each);
// same thread owns same col across entries -> no race, no atomics needed.
// ---------------------------------------------------------------------------
__global__ void ovf_fix_kernel(const float* __restrict__ table,
                               const int* __restrict__ remap,
                               const int2* __restrict__ ovf, const int* __restrict__ ovfn,
                               ushort* __restrict__ aggbf) {
    int n = min(*ovfn, OVF_MAX);
    int c = threadIdx.x;
    for (int e = 0; e < n; ++e) {
        int i = ovf[e].x, j = ovf[e].y;
        size_t o = (size_t)remap[i] * EMBED + c;
        float cur = bf2f(aggbf[o]) + 0.5f * table[(size_t)j * EMBED + c];
        aggbf[o] = f2bf(cur);
    }
}

// ---------------------------------------------------------------------------
// fused gather + bf16-MFMA MLP (unchanged structure, now reads bf16 agg)
// ---------------------------------------------------------------------------
__global__ __launch_bounds__(256)
void mlp_mfma_kernel(const int*    __restrict__ tokens,
                     const int*    __restrict__ remap,
                     const ushort* __restrict__ aggbf,
                     const ushort* __restrict__ W1t,   // [512][128] bf16
                     const ushort* __restrict__ W2t,   // [128][512] bf16
                     const float*  __restrict__ b1,
                     const float*  __restrict__ b2,
                     float*        __restrict__ out) {
    __shared__ ushort Xs[TB * EMBED];    // 8 KB, XOR-swizzled (granule16 ^= row&7)
    __shared__ ushort Hs[TB * HIDDEN];   // 32 KB, XOR-swizzled

    const int t    = threadIdx.x;
    const int lane = t & 63;
    const int wv   = t >> 6;
    const int base = blockIdx.x * TB;
    const int l15  = lane & 15;
    const int lhi  = lane >> 4;          // 0..3

    // ---- stage X = aggbf[remap[tokens]] into swizzled LDS ----
    {
        int r   = t >> 3;                // 0..31
        int g0  = (t & 7) * 2;           // two 8-elem granules per thread
        int tok = tokens[base + r];
        const ushort* src = aggbf + (size_t)remap[tok] * EMBED;
        #pragma unroll
        for (int h = 0; h < 2; ++h) {
            int g = g0 + h;
            short8v v = *(const short8v*)(src + g * 8);
            int gs = g ^ (r & 7);
            *(short8v*)&Xs[r * EMBED + gs * 8] = v;
        }
    }
    __syncthreads();

    // ---- GEMM1: H[32][128 per wave] = X @ W1 ----
    f32x4 acc1[2][8];
    #pragma unroll
    for (int n = 0; n < 8; ++n) {
        float bv = b1[wv * 128 + n * 16 + l15];
        #pragma unroll
        for (int m = 0; m < 2; ++m) acc1[m][n] = (f32x4){bv, bv, bv, bv};
    }

    #pragma unroll
    for (int kk = 0; kk < EMBED / 32; ++kk) {       // 4 k-steps
        short8v a[2];
        #pragma unroll
        for (int m = 0; m < 2; ++m) {
            int r = m * 16 + l15;
            int g = (kk * 4 + lhi) ^ (r & 7);
            a[m] = *(const short8v*)&Xs[r * EMBED + g * 8];
        }
        #pragma unroll
        for (int n = 0; n < 8; ++n) {
            int col = wv * 128 + n * 16 + l15;
            short8v b = *(const short8v*)(W1t + col * EMBED + kk * 32 + lhi * 8);
            acc1[0][n] = __builtin_amdgcn_mfma_f32_16x16x32_bf16(a[0], b, acc1[0][n], 0, 0, 0);
            acc1[1][n] = __builtin_amdgcn_mfma_f32_16x16x32_bf16(a[1], b, acc1[1][n], 0, 0, 0);
        }
    }

    // ---- gelu -> bf16 -> swizzled Hs ----
    #pragma unroll
    for (int m = 0; m < 2; ++m)
        #pragma unroll
        for (int n = 0; n < 8; ++n) {
            int col = wv * 128 + n * 16 + l15;
            #pragma unroll
            for (int q = 0; q < 4; ++q) {
                int row = m * 16 + lhi * 4 + q;
                float hv = gelu_fast(acc1[m][n][q]);
                int g = (col >> 3) ^ (row & 7);
                Hs[row * HIDDEN + g * 8 + (col & 7)] = f2bf(hv);
            }
        }
    __syncthreads();

    // ---- GEMM2: out[32][32 per wave] = H @ W2 ----
    f32x4 acc2[2][2] = {};
    #pragma unroll 4
    for (int kk = 0; kk < HIDDEN / 32; ++kk) {      // 16 k-steps
        short8v a[2];
        #pragma unroll
        for (int m = 0; m < 2; ++m) {
            int r = m * 16 + l15;
            int g = (kk * 4 + lhi) ^ (r & 7);
            a[m] = *(const short8v*)&Hs[r * HIDDEN + g * 8];
        }
        #pragma unroll
        for (int n = 0; n < 2; ++n) {
            int col = wv * 32 + n * 16 + l15;
            short8v b = *(const short8v*)(W2t + col * HIDDEN + kk * 32 + lhi * 8);
            acc2[0][n] = __builtin_amdgcn_mfma_f32_16x16x32_bf16(a[0], b, acc2[0][n], 0, 0, 0);
            acc2[1][n] = __builtin_amdgcn_mfma_f32_16x16x32_bf16(a[1], b, acc2[1][n], 0, 0, 0);
        }
    }

    // ---- epilogue: += b2, store ----
    #pragma unroll
    for (int n = 0; n < 2; ++n) {
        int col = wv * 32 + n * 16 + l15;
        float bv = b2[col];
        #pragma unroll
        for (int m = 0; m < 2; ++m)
            #pragma unroll
            for (int q = 0; q < 4; ++q) {
                int row = m * 16 + lhi * 4 + q;
                out[(size_t)(base + row) * EMBED + col] = acc2[m][n][q] + bv;
            }
    }
}

// ---------------------------------------------------------------------------
extern "C" void kernel_launch(void* const* d_in, const int* in_sizes, int n_in,
                              void* d_out, int out_size, void* d_ws, size_t ws_size,
                              hipStream_t stream) {
    const int*   tokens = (const int*)  d_in[0];
    const float* table  = (const float*)d_in[1];
    const int*   bi     = (const int*)  d_in[2];
    const int*   bj     = (const int*)  d_in[3];
    const float* w1     = (const float*)d_in[4];
    const float* b1     = (const float*)d_in[5];
    const float* w2     = (const float*)d_in[6];
    const float* b2     = (const float*)d_in[7];
    float* out = (float*)d_out;

    const int vocab = in_sizes[1] / EMBED;   // 50257
    const int nk    = in_sizes[2];           // 4 * vocab
    const int ntok  = in_sizes[0];           // 32768

    // ---- workspace layout (~14 MB total) ----
    char* ws = (char*)d_ws;
    size_t off = 0;
    auto alloc = [&](size_t b) { size_t o = off; off += (b + 255) & ~(size_t)255; return o; };
    ushort* aggbf = (ushort*)(ws + alloc((size_t)ntok * EMBED * 2));     // worst case: all unique
    ushort* W1t   = (ushort*)(ws + alloc((size_t)EMBED * HIDDEN * 2));
    ushort* W2t   = (ushort*)(ws + alloc((size_t)EMBED * HIDDEN * 2));
    int*    csr   = (int*)   (ws + alloc((size_t)vocab * CAP * 4));
    int2*   ovf   = (int2*)  (ws + alloc((size_t)OVF_MAX * 8));
    int*    remap = (int*)   (ws + alloc((size_t)vocab * 4));
    size_t zero0 = off;
    int*    cnt   = (int*)   (ws + alloc((size_t)vocab * 4));
    int*    flags = (int*)   (ws + alloc((size_t)vocab * 4));
    int*    ctrs  = (int*)   (ws + alloc(256));                          // [0]=nuniq [1]=ovfn
    size_t zeroBytes = off - zero0;

    hipMemsetAsync(ws + zero0, 0, zeroBytes, stream);

    flag_remap_kernel<<<(ntok + 255) / 256, 256, 0, stream>>>(tokens, flags, remap, ctrs + 0, ntok);
    conv_t_kernel<<<(2 * EMBED * HIDDEN) / 256, 256, 0, stream>>>(w1, w2, W1t, W2t);
    bucket_kernel<<<(nk + 255) / 256, 256, 0, stream>>>(bi, bj, flags, cnt, csr, ovf, ctrs + 1, nk);
    agg_build_kernel<<<(vocab * 64 + 255) / 256, 256, 0, stream>>>(table, flags, remap, cnt, csr, aggbf, vocab);
    ovf_fix_kernel<<<1, 128, 0, stream>>>(table, remap, ovf, ctrs + 1, aggbf);
    mlp_mfma_kernel<<<ntok / TB, 256, 0, stream>>>(tokens, remap, aggbf, W1t, W2t, b1, b2, out);
}